// Round 5
// baseline (238.979 us; speedup 1.0000x reference)
//
#include <hip/hip_runtime.h>

typedef __attribute__((ext_vector_type(8))) short bf16x8;
typedef __attribute__((ext_vector_type(4))) short short4v;
typedef __attribute__((ext_vector_type(4))) float f32x4;
typedef __attribute__((ext_vector_type(16))) float f32x16;
typedef __attribute__((ext_vector_type(4))) float float4v;
typedef unsigned short ushort_t;

__device__ __forceinline__ unsigned short f2bf(float x) {
    unsigned u = __float_as_uint(x);
    return (unsigned short)((u + 0x7fffu + ((u >> 16) & 1u)) >> 16);
}
__device__ __forceinline__ float bf2f(unsigned short b) {
    return __uint_as_float(((unsigned)b) << 16);
}
__device__ __forceinline__ f32x4 mfma16(bf16x8 a, bf16x8 b, f32x4 c) {
    return __builtin_amdgcn_mfma_f32_16x16x32_bf16(a, b, c, 0, 0, 0);
}
__device__ __forceinline__ f32x16 mfma32(bf16x8 a, bf16x8 b, f32x16 c) {
    return __builtin_amdgcn_mfma_f32_32x32x16_bf16(a, b, c, 0, 0, 0);
}
__device__ __forceinline__ unsigned cvtpk(float lo, float hi) {
    unsigned r;
    asm("v_cvt_pk_bf16_f32 %0, %1, %2" : "=v"(r) : "v"(lo), "v"(hi));
    return r;
}
__device__ __forceinline__ bf16x8 pack4(unsigned w0, unsigned w1, unsigned w2, unsigned w3) {
    union { unsigned u[4]; bf16x8 v; } c;
    c.u[0] = w0; c.u[1] = w1; c.u[2] = w2; c.u[3] = w3;
    return c.v;
}

constexpr int GK = 1024;

// ------------------------------------------------------------------
// Elementwise split: f32 -> (hi, lo) bf16. n4 = N/4.
// ------------------------------------------------------------------
__global__ __launch_bounds__(256)
void split_kernel(const float* __restrict__ in, ushort_t* __restrict__ hi,
                  ushort_t* __restrict__ lo, int n4)
{
    int i = blockIdx.x * blockDim.x + threadIdx.x;
    const int stride = gridDim.x * blockDim.x;
    for (; i < n4; i += stride) {
        float4v v = ((const float4v*)in)[i];
        short4v h, l;
        #pragma unroll
        for (int j = 0; j < 4; ++j) {
            unsigned short hb = f2bf(v[j]);
            h[j] = (short)hb;
            l[j] = (short)f2bf(v[j] - bf2f(hb));
        }
        ((short4v*)hi)[i] = h;
        ((short4v*)lo)[i] = l;
    }
}

// ------------------------------------------------------------------
// Elementwise convert: f32 -> bf16 (round-to-nearest). n4 = N/4.
// ------------------------------------------------------------------
__global__ __launch_bounds__(256)
void cvt_kernel(const float* __restrict__ in, ushort_t* __restrict__ out, int n4)
{
    int i = blockIdx.x * blockDim.x + threadIdx.x;
    const int stride = gridDim.x * blockDim.x;
    for (; i < n4; i += stride) {
        float4v v = ((const float4v*)in)[i];
        short4v h;
        #pragma unroll
        for (int j = 0; j < 4; ++j) h[j] = (short)f2bf(v[j]);
        ((short4v*)out)[i] = h;
    }
}

// ------------------------------------------------------------------
// Split GEMM (Q/K projections): pre-split bf16 inputs, 3-MFMA hi/lo,
// reg-prefetch pipeline. M=4096, N=K=1024, BM=128, BN=64, BK=64.
// ------------------------------------------------------------------
constexpr int SBM = 128, SBN = 64, SLD = 72;

__global__ __launch_bounds__(256)
void gemm_split(const ushort_t* __restrict__ Ahi, const ushort_t* __restrict__ Alo,
                const ushort_t* __restrict__ Bhi, const ushort_t* __restrict__ Blo,
                const float* __restrict__ bias,
                ushort_t* __restrict__ Ohi, ushort_t* __restrict__ Olo)
{
    __shared__ alignas(16) short Ah[SBM * SLD], Al[SBM * SLD];
    __shared__ alignas(16) short Bh[SBN * SLD], Bl[SBN * SLD];

    const int tid = threadIdx.x, lane = tid & 63, wv = tid >> 6;
    const int lr = lane & 15, lg = lane >> 4;
    const int m0 = blockIdx.y * SBM, n0 = blockIdx.x * SBN;
    const int wm = (wv >> 1) * 64, wn = (wv & 1) * 32;
    const int r8 = tid >> 3, c8 = (tid & 7) * 8;

    f32x4 acc[4][2] = {};
    bf16x8 pah[4], pal[4], pbh[2], pbl[2];

    auto load_tiles = [&](int k0) {
        #pragma unroll
        for (int i = 0; i < 4; ++i) {
            const size_t off = (size_t)(m0 + r8 + 32 * i) * GK + k0 + c8;
            pah[i] = *(const bf16x8*)(Ahi + off);
            pal[i] = *(const bf16x8*)(Alo + off);
        }
        #pragma unroll
        for (int i = 0; i < 2; ++i) {
            const size_t off = (size_t)(n0 + r8 + 32 * i) * GK + k0 + c8;
            pbh[i] = *(const bf16x8*)(Bhi + off);
            pbl[i] = *(const bf16x8*)(Blo + off);
        }
    };

    load_tiles(0);

    for (int k0 = 0; k0 < GK; k0 += 64) {
        __syncthreads();
        #pragma unroll
        for (int i = 0; i < 4; ++i) {
            *(bf16x8*)(Ah + (r8 + 32 * i) * SLD + c8) = pah[i];
            *(bf16x8*)(Al + (r8 + 32 * i) * SLD + c8) = pal[i];
        }
        #pragma unroll
        for (int i = 0; i < 2; ++i) {
            *(bf16x8*)(Bh + (r8 + 32 * i) * SLD + c8) = pbh[i];
            *(bf16x8*)(Bl + (r8 + 32 * i) * SLD + c8) = pbl[i];
        }
        __syncthreads();
        if (k0 + 64 < GK) load_tiles(k0 + 64);

        #pragma unroll
        for (int ks = 0; ks < 2; ++ks) {
            bf16x8 af[4], afl[4], bfr[2], bfl[2];
            #pragma unroll
            for (int mi = 0; mi < 4; ++mi) {
                const int row = wm + mi * 16 + lr;
                af[mi]  = *(const bf16x8*)(Ah + row * SLD + ks * 32 + lg * 8);
                afl[mi] = *(const bf16x8*)(Al + row * SLD + ks * 32 + lg * 8);
            }
            #pragma unroll
            for (int ni = 0; ni < 2; ++ni) {
                const int row = wn + ni * 16 + lr;
                bfr[ni] = *(const bf16x8*)(Bh + row * SLD + ks * 32 + lg * 8);
                bfl[ni] = *(const bf16x8*)(Bl + row * SLD + ks * 32 + lg * 8);
            }
            #pragma unroll
            for (int mi = 0; mi < 4; ++mi)
                #pragma unroll
                for (int ni = 0; ni < 2; ++ni) {
                    acc[mi][ni] = mfma16(af[mi],  bfr[ni], acc[mi][ni]);
                    acc[mi][ni] = mfma16(af[mi],  bfl[ni], acc[mi][ni]);
                    acc[mi][ni] = mfma16(afl[mi], bfr[ni], acc[mi][ni]);
                }
        }
    }

    #pragma unroll
    for (int mi = 0; mi < 4; ++mi)
        #pragma unroll
        for (int ni = 0; ni < 2; ++ni) {
            const int gr = m0 + wm + mi * 16 + lg * 4;
            const int gc = n0 + wn + ni * 16 + lr;
            const float bv = bias[gc];
            #pragma unroll
            for (int r = 0; r < 4; ++r) {
                float val = acc[mi][ni][r] + bv;
                unsigned short hb = f2bf(val);
                Ohi[(size_t)(gr + r) * GK + gc] = hb;
                Olo[(size_t)(gr + r) * GK + gc] = f2bf(val - bf2f(hb));
            }
        }
}

// ------------------------------------------------------------------
// Mixed GEMM, plain bf16 single-MFMA, reg-prefetch pipeline.
// MODE 0 (V^T): A = w_v bf16 [1024][1024], B = values bf16 [4096][1024],
//               out bf16 C[m][n] (ld 4096), bias per ROW.
// MODE 1 (O):   A = Mb bf16 [4096][1024], B = w_o f32 [1024][1024],
//               out f32 (ld 1024), bias per COL.
// ------------------------------------------------------------------
template<int MODE>
__global__ __launch_bounds__(256)
void gemm_mixed(const ushort_t* __restrict__ Ap, const void* __restrict__ Bp,
                const float* __restrict__ bias, void* __restrict__ Op)
{
    __shared__ alignas(16) short Ah[SBM * SLD];
    __shared__ alignas(16) short Bh[SBN * SLD];

    const int tid = threadIdx.x, lane = tid & 63, wv = tid >> 6;
    const int lr = lane & 15, lg = lane >> 4;
    const int m0 = blockIdx.y * SBM, n0 = blockIdx.x * SBN;
    const int wm = (wv >> 1) * 64, wn = (wv & 1) * 32;
    const int r8 = tid >> 3, c8 = (tid & 7) * 8;
    const int r16 = tid >> 4, c4 = (tid & 15) * 4;

    f32x4 acc[4][2] = {};
    bf16x8 pa[4], pb[2];
    float4v pbf[4];

    auto load_tiles = [&](int k0) {
        #pragma unroll
        for (int i = 0; i < 4; ++i)
            pa[i] = *(const bf16x8*)(Ap + (size_t)(m0 + r8 + 32 * i) * GK + k0 + c8);
        if (MODE == 0) {
            const ushort_t* B = (const ushort_t*)Bp;
            #pragma unroll
            for (int i = 0; i < 2; ++i)
                pb[i] = *(const bf16x8*)(B + (size_t)(n0 + r8 + 32 * i) * GK + k0 + c8);
        } else {
            const float* B = (const float*)Bp;
            #pragma unroll
            for (int i = 0; i < 4; ++i)
                pbf[i] = *(const float4v*)(B + (size_t)(n0 + r16 + 16 * i) * GK + k0 + c4);
        }
    };

    load_tiles(0);

    for (int k0 = 0; k0 < GK; k0 += 64) {
        __syncthreads();
        #pragma unroll
        for (int i = 0; i < 4; ++i)
            *(bf16x8*)(Ah + (r8 + 32 * i) * SLD + c8) = pa[i];
        if (MODE == 0) {
            #pragma unroll
            for (int i = 0; i < 2; ++i)
                *(bf16x8*)(Bh + (r8 + 32 * i) * SLD + c8) = pb[i];
        } else {
            #pragma unroll
            for (int i = 0; i < 4; ++i) {
                short4v h;
                #pragma unroll
                for (int j = 0; j < 4; ++j) h[j] = (short)f2bf(pbf[i][j]);
                *(short4v*)(Bh + (r16 + 16 * i) * SLD + c4) = h;
            }
        }
        __syncthreads();
        if (k0 + 64 < GK) load_tiles(k0 + 64);

        #pragma unroll
        for (int ks = 0; ks < 2; ++ks) {
            bf16x8 af[4], bfr[2];
            #pragma unroll
            for (int mi = 0; mi < 4; ++mi)
                af[mi] = *(const bf16x8*)(Ah + (wm + mi * 16 + lr) * SLD + ks * 32 + lg * 8);
            #pragma unroll
            for (int ni = 0; ni < 2; ++ni)
                bfr[ni] = *(const bf16x8*)(Bh + (wn + ni * 16 + lr) * SLD + ks * 32 + lg * 8);
            #pragma unroll
            for (int mi = 0; mi < 4; ++mi)
                #pragma unroll
                for (int ni = 0; ni < 2; ++ni)
                    acc[mi][ni] = mfma16(af[mi], bfr[ni], acc[mi][ni]);
        }
    }

    #pragma unroll
    for (int mi = 0; mi < 4; ++mi)
        #pragma unroll
        for (int ni = 0; ni < 2; ++ni) {
            const int gr = m0 + wm + mi * 16 + lg * 4;
            const int gc = n0 + wn + ni * 16 + lr;
            #pragma unroll
            for (int r = 0; r < 4; ++r) {
                if (MODE == 0) {
                    float val = acc[mi][ni][r] + bias[gr + r];
                    ((ushort_t*)Op)[(size_t)(gr + r) * 4096 + gc] = f2bf(val);
                } else {
                    float val = acc[mi][ni][r] + bias[gc];
                    ((float*)Op)[(size_t)(gr + r) * 1024 + gc] = val;
                }
            }
        }
}

// ------------------------------------------------------------------
// Flash attention v5: K-split across wave pairs for 2x occupancy.
// Block = 256 thr = 4 waves = 2 q-groups x 2 K-halves; 64 q-rows/block.
// Wave (qg,khalf) handles q-rows [qg*32,qg*32+32), keys khalf*32+[0,32)
// of every 64-key tile. Online softmax per wave (defer-max); pairs
// merged via LDS at the end. Grid 1024 -> 4 blocks/CU, 16 waves/CU.
// ------------------------------------------------------------------
constexpr int SEQ = 2048, DM = 1024;

__device__ __forceinline__ bf16x8 lds_rd(const short* base, int row, int chunk) {
    return *(const bf16x8*)(base + row * 64 + ((chunk * 8) ^ ((row & 7) << 3)));
}

__global__ __launch_bounds__(256, 4)
void attn5_kernel(const ushort_t* __restrict__ Qhi, const ushort_t* __restrict__ Qlo,
                  const ushort_t* __restrict__ Khi, const ushort_t* __restrict__ Klo,
                  const ushort_t* __restrict__ Vt,  ushort_t* __restrict__ Mrg)
{
    __shared__ alignas(16) short smem[3 * 64 * 64];
    short* Ksh = smem;
    short* Ksl = smem + 4096;
    short* Vsm = smem + 8192;

    const int tid = threadIdx.x, lane = tid & 63, wv = tid >> 6;
    const int l31 = lane & 31, lg2 = lane >> 5;
    const int qg = wv >> 1, khalf = wv & 1;

    const int f = blockIdx.y * 32 + blockIdx.x;      // 0..1023
    const int g = (f & 7) * 128 + (f >> 3);          // bijective XCD swizzle
    const int qt = g & 31, bh = g >> 5;
    const int b = bh >> 4, h = bh & 15;
    const size_t seq0 = (size_t)b * SEQ;
    const int col0 = h * 64;

    // Q fragments (B-operand): q = l31, k = kc*16 + lg2*8 + j
    const int qrow = qt * 64 + qg * 32 + l31;
    bf16x8 qh[4], ql[4];
    #pragma unroll
    for (int kc = 0; kc < 4; ++kc) {
        const size_t off = (seq0 + qrow) * DM + col0 + kc * 16 + lg2 * 8;
        qh[kc] = *(const bf16x8*)(Qhi + off);
        ql[kc] = *(const bf16x8*)(Qlo + off);
    }

    f32x16 accT0 = {}, accT1 = {};      // O^T: col=q, rows d / d+32
    float m_run = -1e30f, l_run = 0.f;  // m on 0.125-scaled scores; l lane-partial

    const int sr = tid >> 3, sc8 = (tid & 7) * 8;
    const int kb = khalf * 32;          // wave's key rows in LDS
    const int cb = khalf * 4;           // wave's V key-chunk base

    bf16x8 gkh[2], gkl[2], gvv[2];
    #pragma unroll
    for (int p = 0; p < 2; ++p) {
        const int row = sr + 32 * p;
        const size_t koff = (seq0 + row) * DM + col0 + sc8;
        gkh[p] = *(const bf16x8*)(Khi + koff);
        gkl[p] = *(const bf16x8*)(Klo + koff);
        gvv[p] = *(const bf16x8*)(Vt + (size_t)(col0 + row) * 4096 + seq0 + sc8);
    }

    for (int kt = 0; kt < SEQ; kt += 64) {
        __syncthreads();
        #pragma unroll
        for (int p = 0; p < 2; ++p) {
            const int row = sr + 32 * p;
            const int wi = row * 64 + (sc8 ^ ((row & 7) << 3));
            *(bf16x8*)(Ksh + wi) = gkh[p];
            *(bf16x8*)(Ksl + wi) = gkl[p];
            *(bf16x8*)(Vsm + wi) = gvv[p];
        }
        __syncthreads();

        {   // prefetch next tile
            const int ktn = (kt + 64 < SEQ) ? kt + 64 : kt;
            #pragma unroll
            for (int p = 0; p < 2; ++p) {
                const int row = sr + 32 * p;
                const size_t koff = (seq0 + ktn + row) * DM + col0 + sc8;
                gkh[p] = *(const bf16x8*)(Khi + koff);
                gkl[p] = *(const bf16x8*)(Klo + koff);
                gvv[p] = *(const bf16x8*)(Vt + (size_t)(col0 + row) * 4096 + seq0 + ktn + sc8);
            }
        }

        // ---- S^T for this wave's 32 keys (hi/lo 3-MFMA) ----
        f32x16 s0 = {};
        #pragma unroll
        for (int kc = 0; kc < 4; ++kc) {
            const int c = kc * 2 + lg2;
            bf16x8 kh0 = lds_rd(Ksh, kb + l31, c);
            bf16x8 kl0 = lds_rd(Ksl, kb + l31, c);
            s0 = mfma32(kh0, qh[kc], s0);
            s0 = mfma32(kl0, qh[kc], s0);
            s0 = mfma32(kh0, ql[kc], s0);
        }

        // ---- online softmax, defer-max ----
        float mx = s0[0];
        #pragma unroll
        for (int i = 1; i < 16; ++i) mx = fmaxf(mx, s0[i]);
        float mxs = mx * 0.125f;
        mxs = fmaxf(mxs, __shfl_xor(mxs, 32));
        if (__any(mxs > m_run + 6.0f)) {
            const float mn    = fmaxf(m_run, mxs);
            const float alpha = __expf(m_run - mn);
            m_run = mn;
            l_run *= alpha;
            #pragma unroll
            for (int i = 0; i < 16; ++i) { accT0[i] *= alpha; accT1[i] *= alpha; }
        }
        float rs = 0.f;
        #pragma unroll
        for (int i = 0; i < 16; ++i) {
            float p = __expf(fmaf(s0[i], 0.125f, -m_run));
            s0[i] = p; rs += p;
        }
        l_run += rs;

        // ---- pack P (32 keys) -> pa[2] PV B-frags ----
        unsigned pk0[4][2];
        #pragma unroll
        for (int m = 0; m < 4; ++m) {
            pk0[m][0] = cvtpk(s0[4 * m],     s0[4 * m + 1]);
            pk0[m][1] = cvtpk(s0[4 * m + 2], s0[4 * m + 3]);
        }
        bf16x8 pa[2];
        #pragma unroll
        for (int u = 0; u < 2; ++u) {
            const unsigned pe0 = pk0[2 * u][0],     pe1 = pk0[2 * u][1];
            const unsigned po0 = pk0[2 * u + 1][0], po1 = pk0[2 * u + 1][1];
            const unsigned sd0 = lg2 ? pe0 : po0;
            const unsigned sd1 = lg2 ? pe1 : po1;
            const unsigned rc0 = (unsigned)__shfl_xor((int)sd0, 32);
            const unsigned rc1 = (unsigned)__shfl_xor((int)sd1, 32);
            const unsigned a0 = lg2 ? rc0 : pe0;
            const unsigned a1 = lg2 ? rc1 : pe1;
            const unsigned a2 = lg2 ? po0 : rc0;
            const unsigned a3 = lg2 ? po1 : rc1;
            pa[u] = pack4(a0, a1, a2, a3);
        }

        // ---- O^T += V^T P over this wave's keys ----
        #pragma unroll
        for (int u = 0; u < 2; ++u) {
            const int c = cb + u * 2 + lg2;
            bf16x8 v0 = lds_rd(Vsm, l31,      c);
            bf16x8 v1 = lds_rd(Vsm, l31 + 32, c);
            accT0 = mfma32(v0, pa[u], accT0);
            accT1 = mfma32(v1, pa[u], accT1);
        }
    }

    // ---- merge khalf pairs via LDS, then store ----
    const float lfull = l_run + __shfl_xor(l_run, 32);
    float* ex = (float*)smem;
    float* slot = ex + (qg * 64 + lane) * 34;
    __syncthreads();
    if (khalf == 1) {
        slot[0] = m_run; slot[1] = lfull;
        #pragma unroll
        for (int i = 0; i < 16; ++i) { slot[2 + i] = accT0[i]; slot[18 + i] = accT1[i]; }
    }
    __syncthreads();
    if (khalf == 0) {
        const float mCp = slot[0], lp = slot[1];
        const float mn = fmaxf(m_run, mCp);
        const float a0 = __expf(m_run - mn);
        const float a1 = __expf(mCp - mn);
        const float inv = 1.0f / (lfull * a0 + lp * a1);
        #pragma unroll
        for (int reg = 0; reg < 16; ++reg) {
            const int d = (reg & 3) + 8 * (reg >> 2) + 4 * lg2;
            float o0 = (accT0[reg] * a0 + slot[2 + reg]  * a1) * inv;
            float o1 = (accT1[reg] * a0 + slot[18 + reg] * a1) * inv;
            Mrg[(seq0 + qrow) * DM + col0 + d]      = f2bf(o0);
            Mrg[(seq0 + qrow) * DM + col0 + d + 32] = f2bf(o1);
        }
    }
}

// ------------------------------------------------------------------
extern "C" void kernel_launch(void* const* d_in, const int* in_sizes, int n_in,
                              void* d_out, int out_size, void* d_ws, size_t ws_size,
                              hipStream_t stream)
{
    const float* queries = (const float*)d_in[0];
    const float* keys    = (const float*)d_in[1];
    const float* values  = (const float*)d_in[2];
    const float* w_q = (const float*)d_in[3];
    const float* b_q = (const float*)d_in[4];
    const float* w_k = (const float*)d_in[5];
    const float* b_k = (const float*)d_in[6];
    const float* w_v = (const float*)d_in[7];
    const float* b_v = (const float*)d_in[8];
    const float* w_o = (const float*)d_in[9];
    const float* b_o = (const float*)d_in[10];

    const size_t MB = 1u << 20;
    char* ws = (char*)d_ws;
    ushort_t* q_hi   = (ushort_t*)(ws);            // [0,8)
    ushort_t* q_lo   = (ushort_t*)(ws + 8 * MB);   // [8,16)
    ushort_t* Khi    = (ushort_t*)(ws);            // [0,8)   after K-proj
    ushort_t* Klo    = (ushort_t*)(ws + 8 * MB);   // [8,16)
    ushort_t* Qhi    = (ushort_t*)(ws + 16 * MB);  // [16,24)
    ushort_t* Qlo    = (ushort_t*)(ws + 24 * MB);  // [24,32)
    ushort_t* Vt     = (ushort_t*)(ws + 32 * MB);  // [32,40)
    ushort_t* Mb     = (ushort_t*)(ws + 40 * MB);  // [40,48)
    ushort_t* wsp_hi = (ushort_t*)(ws + 40 * MB);  // weight split scratch (pre-attn)
    ushort_t* wsp_lo = (ushort_t*)(ws + 42 * MB);
    ushort_t* k_hi   = (ushort_t*)d_out;                    // keys split in d_out
    ushort_t* k_lo   = (ushort_t*)((char*)d_out + 8 * MB);
    ushort_t* vbf    = (ushort_t*)d_out;                    // values bf16 (after K-proj)
    ushort_t* wvbf   = (ushort_t*)((char*)d_out + 8 * MB);  // w_v bf16

    const int n4_act = 4096 * 1024 / 4, n4_w = 1024 * 1024 / 4;
    dim3 blk(256);

    hipLaunchKernelGGL(split_kernel, dim3(2048), blk, 0, stream, queries, q_hi, q_lo, n4_act);
    hipLaunchKernelGGL(split_kernel, dim3(2048), blk, 0, stream, keys, k_hi, k_lo, n4_act);
    hipLaunchKernelGGL(split_kernel, dim3(1024), blk, 0, stream, w_q, wsp_hi, wsp_lo, n4_w);
    hipLaunchKernelGGL(gemm_split, dim3(16, 32), blk, 0, stream,
                       q_hi, q_lo, wsp_hi, wsp_lo, b_q, Qhi, Qlo);
    hipLaunchKernelGGL(split_kernel, dim3(1024), blk, 0, stream, w_k, wsp_hi, wsp_lo, n4_w);
    hipLaunchKernelGGL(gemm_split, dim3(16, 32), blk, 0, stream,
                       k_hi, k_lo, wsp_hi, wsp_lo, b_k, Khi, Klo);
    // keys split in d_out now dead -> reuse d_out for bf16 copies of values, w_v
    hipLaunchKernelGGL(cvt_kernel, dim3(2048), blk, 0, stream, values, vbf, n4_act);
    hipLaunchKernelGGL(cvt_kernel, dim3(1024), blk, 0, stream, w_v, wvbf, n4_w);
    hipLaunchKernelGGL((gemm_mixed<0>), dim3(64, 8), blk, 0, stream, wvbf, vbf, b_v, Vt);
    hipLaunchKernelGGL(attn5_kernel, dim3(32, 32), blk, 0, stream, Qhi, Qlo, Khi, Klo, Vt, Mb);
    hipLaunchKernelGGL((gemm_mixed<1>), dim3(16, 32), blk, 0, stream, Mb, w_o, b_o, (float*)d_out);
}

// Round 7
// 222.367 us; speedup vs baseline: 1.0747x; 1.0747x over previous
//
#include <hip/hip_runtime.h>

typedef __attribute__((ext_vector_type(8))) short bf16x8;
typedef __attribute__((ext_vector_type(4))) short short4v;
typedef __attribute__((ext_vector_type(4))) float f32x4;
typedef __attribute__((ext_vector_type(16))) float f32x16;
typedef __attribute__((ext_vector_type(4))) float float4v;
typedef unsigned short ushort_t;

__device__ __forceinline__ unsigned short f2bf(float x) {
    unsigned u = __float_as_uint(x);
    return (unsigned short)((u + 0x7fffu + ((u >> 16) & 1u)) >> 16);
}
__device__ __forceinline__ float bf2f(unsigned short b) {
    return __uint_as_float(((unsigned)b) << 16);
}
__device__ __forceinline__ f32x4 mfma16(bf16x8 a, bf16x8 b, f32x4 c) {
    return __builtin_amdgcn_mfma_f32_16x16x32_bf16(a, b, c, 0, 0, 0);
}
__device__ __forceinline__ f32x16 mfma32(bf16x8 a, bf16x8 b, f32x16 c) {
    return __builtin_amdgcn_mfma_f32_32x32x16_bf16(a, b, c, 0, 0, 0);
}
__device__ __forceinline__ unsigned cvtpk(float lo, float hi) {
    unsigned r;
    asm("v_cvt_pk_bf16_f32 %0, %1, %2" : "=v"(r) : "v"(lo), "v"(hi));
    return r;
}
__device__ __forceinline__ bf16x8 pack4(unsigned w0, unsigned w1, unsigned w2, unsigned w3) {
    union { unsigned u[4]; bf16x8 v; } c;
    c.u[0] = w0; c.u[1] = w1; c.u[2] = w2; c.u[3] = w3;
    return c.v;
}

constexpr int GK = 1024;

// ------------------------------------------------------------------
// Elementwise split: f32 -> (hi, lo) bf16. n4 = N/4.
// ------------------------------------------------------------------
__global__ __launch_bounds__(256)
void split_kernel(const float* __restrict__ in, ushort_t* __restrict__ hi,
                  ushort_t* __restrict__ lo, int n4)
{
    int i = blockIdx.x * blockDim.x + threadIdx.x;
    const int stride = gridDim.x * blockDim.x;
    for (; i < n4; i += stride) {
        float4v v = ((const float4v*)in)[i];
        short4v h, l;
        #pragma unroll
        for (int j = 0; j < 4; ++j) {
            unsigned short hb = f2bf(v[j]);
            h[j] = (short)hb;
            l[j] = (short)f2bf(v[j] - bf2f(hb));
        }
        ((short4v*)hi)[i] = h;
        ((short4v*)lo)[i] = l;
    }
}

// ------------------------------------------------------------------
// Elementwise convert: f32 -> bf16 (round-to-nearest). n4 = N/4.
// ------------------------------------------------------------------
__global__ __launch_bounds__(256)
void cvt_kernel(const float* __restrict__ in, ushort_t* __restrict__ out, int n4)
{
    int i = blockIdx.x * blockDim.x + threadIdx.x;
    const int stride = gridDim.x * blockDim.x;
    for (; i < n4; i += stride) {
        float4v v = ((const float4v*)in)[i];
        short4v h;
        #pragma unroll
        for (int j = 0; j < 4; ++j) h[j] = (short)f2bf(v[j]);
        ((short4v*)out)[i] = h;
    }
}

// ------------------------------------------------------------------
// Split GEMM (Q/K projections): pre-split bf16 inputs, 3-MFMA hi/lo,
// reg-prefetch pipeline. M=4096, N=K=1024, BM=128, BN=64, BK=64.
// ------------------------------------------------------------------
constexpr int SBM = 128, SBN = 64, SLD = 72;

__global__ __launch_bounds__(256)
void gemm_split(const ushort_t* __restrict__ Ahi, const ushort_t* __restrict__ Alo,
                const ushort_t* __restrict__ Bhi, const ushort_t* __restrict__ Blo,
                const float* __restrict__ bias,
                ushort_t* __restrict__ Ohi, ushort_t* __restrict__ Olo)
{
    __shared__ alignas(16) short Ah[SBM * SLD], Al[SBM * SLD];
    __shared__ alignas(16) short Bh[SBN * SLD], Bl[SBN * SLD];

    const int tid = threadIdx.x, lane = tid & 63, wv = tid >> 6;
    const int lr = lane & 15, lg = lane >> 4;
    const int m0 = blockIdx.y * SBM, n0 = blockIdx.x * SBN;
    const int wm = (wv >> 1) * 64, wn = (wv & 1) * 32;
    const int r8 = tid >> 3, c8 = (tid & 7) * 8;

    f32x4 acc[4][2] = {};
    bf16x8 pah[4], pal[4], pbh[2], pbl[2];

    auto load_tiles = [&](int k0) {
        #pragma unroll
        for (int i = 0; i < 4; ++i) {
            const size_t off = (size_t)(m0 + r8 + 32 * i) * GK + k0 + c8;
            pah[i] = *(const bf16x8*)(Ahi + off);
            pal[i] = *(const bf16x8*)(Alo + off);
        }
        #pragma unroll
        for (int i = 0; i < 2; ++i) {
            const size_t off = (size_t)(n0 + r8 + 32 * i) * GK + k0 + c8;
            pbh[i] = *(const bf16x8*)(Bhi + off);
            pbl[i] = *(const bf16x8*)(Blo + off);
        }
    };

    load_tiles(0);

    for (int k0 = 0; k0 < GK; k0 += 64) {
        __syncthreads();
        #pragma unroll
        for (int i = 0; i < 4; ++i) {
            *(bf16x8*)(Ah + (r8 + 32 * i) * SLD + c8) = pah[i];
            *(bf16x8*)(Al + (r8 + 32 * i) * SLD + c8) = pal[i];
        }
        #pragma unroll
        for (int i = 0; i < 2; ++i) {
            *(bf16x8*)(Bh + (r8 + 32 * i) * SLD + c8) = pbh[i];
            *(bf16x8*)(Bl + (r8 + 32 * i) * SLD + c8) = pbl[i];
        }
        __syncthreads();
        if (k0 + 64 < GK) load_tiles(k0 + 64);

        #pragma unroll
        for (int ks = 0; ks < 2; ++ks) {
            bf16x8 af[4], afl[4], bfr[2], bfl[2];
            #pragma unroll
            for (int mi = 0; mi < 4; ++mi) {
                const int row = wm + mi * 16 + lr;
                af[mi]  = *(const bf16x8*)(Ah + row * SLD + ks * 32 + lg * 8);
                afl[mi] = *(const bf16x8*)(Al + row * SLD + ks * 32 + lg * 8);
            }
            #pragma unroll
            for (int ni = 0; ni < 2; ++ni) {
                const int row = wn + ni * 16 + lr;
                bfr[ni] = *(const bf16x8*)(Bh + row * SLD + ks * 32 + lg * 8);
                bfl[ni] = *(const bf16x8*)(Bl + row * SLD + ks * 32 + lg * 8);
            }
            #pragma unroll
            for (int mi = 0; mi < 4; ++mi)
                #pragma unroll
                for (int ni = 0; ni < 2; ++ni) {
                    acc[mi][ni] = mfma16(af[mi],  bfr[ni], acc[mi][ni]);
                    acc[mi][ni] = mfma16(af[mi],  bfl[ni], acc[mi][ni]);
                    acc[mi][ni] = mfma16(afl[mi], bfr[ni], acc[mi][ni]);
                }
        }
    }

    #pragma unroll
    for (int mi = 0; mi < 4; ++mi)
        #pragma unroll
        for (int ni = 0; ni < 2; ++ni) {
            const int gr = m0 + wm + mi * 16 + lg * 4;
            const int gc = n0 + wn + ni * 16 + lr;
            const float bv = bias[gc];
            #pragma unroll
            for (int r = 0; r < 4; ++r) {
                float val = acc[mi][ni][r] + bv;
                unsigned short hb = f2bf(val);
                Ohi[(size_t)(gr + r) * GK + gc] = hb;
                Olo[(size_t)(gr + r) * GK + gc] = f2bf(val - bf2f(hb));
            }
        }
}

// ------------------------------------------------------------------
// Mixed GEMM, plain bf16 single-MFMA, reg-prefetch pipeline.
// MODE 0 (V^T): A = w_v bf16 [1024][1024], B = values bf16 [4096][1024],
//               out bf16 C[m][n] (ld 4096), bias per ROW.
// MODE 1 (O):   A = Mb bf16 [4096][1024], B = w_o f32 [1024][1024],
//               out f32 (ld 1024), bias per COL.
// ------------------------------------------------------------------
template<int MODE>
__global__ __launch_bounds__(256)
void gemm_mixed(const ushort_t* __restrict__ Ap, const void* __restrict__ Bp,
                const float* __restrict__ bias, void* __restrict__ Op)
{
    __shared__ alignas(16) short Ah[SBM * SLD];
    __shared__ alignas(16) short Bh[SBN * SLD];

    const int tid = threadIdx.x, lane = tid & 63, wv = tid >> 6;
    const int lr = lane & 15, lg = lane >> 4;
    const int m0 = blockIdx.y * SBM, n0 = blockIdx.x * SBN;
    const int wm = (wv >> 1) * 64, wn = (wv & 1) * 32;
    const int r8 = tid >> 3, c8 = (tid & 7) * 8;
    const int r16 = tid >> 4, c4 = (tid & 15) * 4;

    f32x4 acc[4][2] = {};
    bf16x8 pa[4], pb[2];
    float4v pbf[4];

    auto load_tiles = [&](int k0) {
        #pragma unroll
        for (int i = 0; i < 4; ++i)
            pa[i] = *(const bf16x8*)(Ap + (size_t)(m0 + r8 + 32 * i) * GK + k0 + c8);
        if (MODE == 0) {
            const ushort_t* B = (const ushort_t*)Bp;
            #pragma unroll
            for (int i = 0; i < 2; ++i)
                pb[i] = *(const bf16x8*)(B + (size_t)(n0 + r8 + 32 * i) * GK + k0 + c8);
        } else {
            const float* B = (const float*)Bp;
            #pragma unroll
            for (int i = 0; i < 4; ++i)
                pbf[i] = *(const float4v*)(B + (size_t)(n0 + r16 + 16 * i) * GK + k0 + c4);
        }
    };

    load_tiles(0);

    for (int k0 = 0; k0 < GK; k0 += 64) {
        __syncthreads();
        #pragma unroll
        for (int i = 0; i < 4; ++i)
            *(bf16x8*)(Ah + (r8 + 32 * i) * SLD + c8) = pa[i];
        if (MODE == 0) {
            #pragma unroll
            for (int i = 0; i < 2; ++i)
                *(bf16x8*)(Bh + (r8 + 32 * i) * SLD + c8) = pb[i];
        } else {
            #pragma unroll
            for (int i = 0; i < 4; ++i) {
                short4v h;
                #pragma unroll
                for (int j = 0; j < 4; ++j) h[j] = (short)f2bf(pbf[i][j]);
                *(short4v*)(Bh + (r16 + 16 * i) * SLD + c4) = h;
            }
        }
        __syncthreads();
        if (k0 + 64 < GK) load_tiles(k0 + 64);

        #pragma unroll
        for (int ks = 0; ks < 2; ++ks) {
            bf16x8 af[4], bfr[2];
            #pragma unroll
            for (int mi = 0; mi < 4; ++mi)
                af[mi] = *(const bf16x8*)(Ah + (wm + mi * 16 + lr) * SLD + ks * 32 + lg * 8);
            #pragma unroll
            for (int ni = 0; ni < 2; ++ni)
                bfr[ni] = *(const bf16x8*)(Bh + (wn + ni * 16 + lr) * SLD + ks * 32 + lg * 8);
            #pragma unroll
            for (int mi = 0; mi < 4; ++mi)
                #pragma unroll
                for (int ni = 0; ni < 2; ++ni)
                    acc[mi][ni] = mfma16(af[mi], bfr[ni], acc[mi][ni]);
        }
    }

    #pragma unroll
    for (int mi = 0; mi < 4; ++mi)
        #pragma unroll
        for (int ni = 0; ni < 2; ++ni) {
            const int gr = m0 + wm + mi * 16 + lg * 4;
            const int gc = n0 + wn + ni * 16 + lr;
            #pragma unroll
            for (int r = 0; r < 4; ++r) {
                if (MODE == 0) {
                    float val = acc[mi][ni][r] + bias[gr + r];
                    ((ushort_t*)Op)[(size_t)(gr + r) * 4096 + gc] = f2bf(val);
                } else {
                    float val = acc[mi][ni][r] + bias[gc];
                    ((float*)Op)[(size_t)(gr + r) * 1024 + gc] = val;
                }
            }
        }
}

// ------------------------------------------------------------------
// Flash attention v7b: 512-thr / 8-wave blocks = 4 q-groups x 2 K-halves.
// QT=128/block -> staging per key-tile identical to v4, but 16 waves/CU.
// Wave (qg,khalf): q-rows qt*128+qg*32+[0,32), keys khalf*32+[0,32) of
// each 64-key tile. In-register softmax (defer-max), cvtpk+shfl P-frags,
// LDS merge of khalf pairs at the end.
// LDS sized for max(staging 24576 B, merge 256*34*4 = 34816 B).  <-- r6 fix
// ------------------------------------------------------------------
constexpr int SEQ = 2048, DM = 1024;

__device__ __forceinline__ bf16x8 lds_rd(const short* base, int row, int chunk) {
    return *(const bf16x8*)(base + row * 64 + ((chunk * 8) ^ ((row & 7) << 3)));
}

__global__ __launch_bounds__(512, 4)
void attn7_kernel(const ushort_t* __restrict__ Qhi, const ushort_t* __restrict__ Qlo,
                  const ushort_t* __restrict__ Khi, const ushort_t* __restrict__ Klo,
                  const ushort_t* __restrict__ Vt,  ushort_t* __restrict__ Mrg)
{
    __shared__ alignas(16) float smem_f[8704];        // 34816 B
    short* smem = (short*)smem_f;
    short* Ksh = smem;                                // staging uses first 24 KB
    short* Ksl = smem + 4096;
    short* Vsm = smem + 8192;

    const int tid = threadIdx.x, lane = tid & 63, wv = tid >> 6;
    const int l31 = lane & 31, lg2 = lane >> 5;
    const int qg = wv >> 1, khalf = wv & 1;

    const int f = blockIdx.y * 16 + blockIdx.x;      // 0..511
    const int g = (f & 7) * 64 + (f >> 3);           // bijective XCD swizzle
    const int qt = g & 15, bh = g >> 4;
    const int b = bh >> 4, h = bh & 15;
    const size_t seq0 = (size_t)b * SEQ;
    const int col0 = h * 64;

    // Q fragments (B-operand): q = l31, k = kc*16 + lg2*8 + j
    const int qrow = qt * 128 + qg * 32 + l31;
    bf16x8 qh[4], ql[4];
    #pragma unroll
    for (int kc = 0; kc < 4; ++kc) {
        const size_t off = (seq0 + qrow) * DM + col0 + kc * 16 + lg2 * 8;
        qh[kc] = *(const bf16x8*)(Qhi + off);
        ql[kc] = *(const bf16x8*)(Qlo + off);
    }

    f32x16 accT0 = {}, accT1 = {};      // O^T: col=q, rows d / d+32
    float m_run = -1e30f, l_run = 0.f;  // m on scaled scores; l lane-partial

    // staging: 512 thr cover a 64x64 tile, one bf16x8 per buffer each
    const int sr = tid >> 3, sc8 = (tid & 7) * 8;
    const int kb = khalf * 32;          // wave's key rows in LDS
    const int cb = khalf * 4;           // wave's V key-chunk base

    bf16x8 gkh, gkl, gvv;
    {
        const size_t koff = (seq0 + sr) * DM + col0 + sc8;
        gkh = *(const bf16x8*)(Khi + koff);
        gkl = *(const bf16x8*)(Klo + koff);
        gvv = *(const bf16x8*)(Vt + (size_t)(col0 + sr) * 4096 + seq0 + sc8);
    }

    for (int kt = 0; kt < SEQ; kt += 64) {
        __syncthreads();
        {
            const int wi = sr * 64 + (sc8 ^ ((sr & 7) << 3));
            *(bf16x8*)(Ksh + wi) = gkh;
            *(bf16x8*)(Ksl + wi) = gkl;
            *(bf16x8*)(Vsm + wi) = gvv;
        }
        __syncthreads();

        {   // prefetch next tile
            const int ktn = (kt + 64 < SEQ) ? kt + 64 : kt;
            const size_t koff = (seq0 + ktn + sr) * DM + col0 + sc8;
            gkh = *(const bf16x8*)(Khi + koff);
            gkl = *(const bf16x8*)(Klo + koff);
            gvv = *(const bf16x8*)(Vt + (size_t)(col0 + sr) * 4096 + seq0 + ktn + sc8);
        }

        // ---- S^T for this wave's 32 keys (hi/lo 3-MFMA) ----
        f32x16 s0 = {};
        #pragma unroll
        for (int kc = 0; kc < 4; ++kc) {
            const int c = kc * 2 + lg2;
            bf16x8 kh0 = lds_rd(Ksh, kb + l31, c);
            bf16x8 kl0 = lds_rd(Ksl, kb + l31, c);
            s0 = mfma32(kh0, qh[kc], s0);
            s0 = mfma32(kl0, qh[kc], s0);
            s0 = mfma32(kh0, ql[kc], s0);
        }

        // ---- online softmax, defer-max ----
        float mx = s0[0];
        #pragma unroll
        for (int i = 1; i < 16; ++i) mx = fmaxf(mx, s0[i]);
        float mxs = mx * 0.125f;
        mxs = fmaxf(mxs, __shfl_xor(mxs, 32));
        if (__any(mxs > m_run + 6.0f)) {
            const float mn    = fmaxf(m_run, mxs);
            const float alpha = __expf(m_run - mn);
            m_run = mn;
            l_run *= alpha;
            #pragma unroll
            for (int i = 0; i < 16; ++i) { accT0[i] *= alpha; accT1[i] *= alpha; }
        }
        float rs = 0.f;
        #pragma unroll
        for (int i = 0; i < 16; ++i) {
            float p = __expf(fmaf(s0[i], 0.125f, -m_run));
            s0[i] = p; rs += p;
        }
        l_run += rs;

        // ---- pack P (32 keys) -> pa[2] PV B-frags ----
        unsigned pk0[4][2];
        #pragma unroll
        for (int m = 0; m < 4; ++m) {
            pk0[m][0] = cvtpk(s0[4 * m],     s0[4 * m + 1]);
            pk0[m][1] = cvtpk(s0[4 * m + 2], s0[4 * m + 3]);
        }
        bf16x8 pa[2];
        #pragma unroll
        for (int u = 0; u < 2; ++u) {
            const unsigned pe0 = pk0[2 * u][0],     pe1 = pk0[2 * u][1];
            const unsigned po0 = pk0[2 * u + 1][0], po1 = pk0[2 * u + 1][1];
            const unsigned sd0 = lg2 ? pe0 : po0;
            const unsigned sd1 = lg2 ? pe1 : po1;
            const unsigned rc0 = (unsigned)__shfl_xor((int)sd0, 32);
            const unsigned rc1 = (unsigned)__shfl_xor((int)sd1, 32);
            const unsigned a0 = lg2 ? rc0 : pe0;
            const unsigned a1 = lg2 ? rc1 : pe1;
            const unsigned a2 = lg2 ? po0 : rc0;
            const unsigned a3 = lg2 ? po1 : rc1;
            pa[u] = pack4(a0, a1, a2, a3);
        }

        // ---- O^T += V^T P over this wave's keys ----
        #pragma unroll
        for (int u = 0; u < 2; ++u) {
            const int c = cb + u * 2 + lg2;
            bf16x8 v0 = lds_rd(Vsm, l31,      c);
            bf16x8 v1 = lds_rd(Vsm, l31 + 32, c);
            accT0 = mfma32(v0, pa[u], accT0);
            accT1 = mfma32(v1, pa[u], accT1);
        }
    }

    // ---- merge khalf pairs via LDS (34816 B buffer), then store ----
    const float lfull = l_run + __shfl_xor(l_run, 32);
    float* slot = smem_f + (qg * 64 + lane) * 34;
    __syncthreads();
    if (khalf == 1) {
        slot[0] = m_run; slot[1] = lfull;
        #pragma unroll
        for (int i = 0; i < 16; ++i) { slot[2 + i] = accT0[i]; slot[18 + i] = accT1[i]; }
    }
    __syncthreads();
    if (khalf == 0) {
        const float mCp = slot[0], lp = slot[1];
        const float mn = fmaxf(m_run, mCp);
        const float a0 = __expf(m_run - mn);
        const float a1 = __expf(mCp - mn);
        const float inv = 1.0f / (lfull * a0 + lp * a1);
        #pragma unroll
        for (int reg = 0; reg < 16; ++reg) {
            const int d = (reg & 3) + 8 * (reg >> 2) + 4 * lg2;
            float o0 = (accT0[reg] * a0 + slot[2 + reg]  * a1) * inv;
            float o1 = (accT1[reg] * a0 + slot[18 + reg] * a1) * inv;
            Mrg[(seq0 + qrow) * DM + col0 + d]      = f2bf(o0);
            Mrg[(seq0 + qrow) * DM + col0 + d + 32] = f2bf(o1);
        }
    }
}

// ------------------------------------------------------------------
extern "C" void kernel_launch(void* const* d_in, const int* in_sizes, int n_in,
                              void* d_out, int out_size, void* d_ws, size_t ws_size,
                              hipStream_t stream)
{
    const float* queries = (const float*)d_in[0];
    const float* keys    = (const float*)d_in[1];
    const float* values  = (const float*)d_in[2];
    const float* w_q = (const float*)d_in[3];
    const float* b_q = (const float*)d_in[4];
    const float* w_k = (const float*)d_in[5];
    const float* b_k = (const float*)d_in[6];
    const float* w_v = (const float*)d_in[7];
    const float* b_v = (const float*)d_in[8];
    const float* w_o = (const float*)d_in[9];
    const float* b_o = (const float*)d_in[10];

    const size_t MB = 1u << 20;
    char* ws = (char*)d_ws;
    ushort_t* q_hi   = (ushort_t*)(ws);            // [0,8)
    ushort_t* q_lo   = (ushort_t*)(ws + 8 * MB);   // [8,16)
    ushort_t* Khi    = (ushort_t*)(ws);            // [0,8)   after K-proj
    ushort_t* Klo    = (ushort_t*)(ws + 8 * MB);   // [8,16)
    ushort_t* Qhi    = (ushort_t*)(ws + 16 * MB);  // [16,24)
    ushort_t* Qlo    = (ushort_t*)(ws + 24 * MB);  // [24,32)
    ushort_t* Vt     = (ushort_t*)(ws + 32 * MB);  // [32,40)
    ushort_t* Mb     = (ushort_t*)(ws + 40 * MB);  // [40,48)
    ushort_t* wsp_hi = (ushort_t*)(ws + 40 * MB);  // weight split scratch (pre-attn)
    ushort_t* wsp_lo = (ushort_t*)(ws + 42 * MB);
    ushort_t* k_hi   = (ushort_t*)d_out;                    // keys split in d_out
    ushort_t* k_lo   = (ushort_t*)((char*)d_out + 8 * MB);
    ushort_t* vbf    = (ushort_t*)d_out;                    // values bf16 (after K-proj)
    ushort_t* wvbf   = (ushort_t*)((char*)d_out + 8 * MB);  // w_v bf16

    const int n4_act = 4096 * 1024 / 4, n4_w = 1024 * 1024 / 4;
    dim3 blk(256);

    hipLaunchKernelGGL(split_kernel, dim3(2048), blk, 0, stream, queries, q_hi, q_lo, n4_act);
    hipLaunchKernelGGL(split_kernel, dim3(2048), blk, 0, stream, keys, k_hi, k_lo, n4_act);
    hipLaunchKernelGGL(split_kernel, dim3(1024), blk, 0, stream, w_q, wsp_hi, wsp_lo, n4_w);
    hipLaunchKernelGGL(gemm_split, dim3(16, 32), blk, 0, stream,
                       q_hi, q_lo, wsp_hi, wsp_lo, b_q, Qhi, Qlo);
    hipLaunchKernelGGL(split_kernel, dim3(1024), blk, 0, stream, w_k, wsp_hi, wsp_lo, n4_w);
    hipLaunchKernelGGL(gemm_split, dim3(16, 32), blk, 0, stream,
                       k_hi, k_lo, wsp_hi, wsp_lo, b_k, Khi, Klo);
    // keys split in d_out now dead -> reuse d_out for bf16 copies of values, w_v
    hipLaunchKernelGGL(cvt_kernel, dim3(2048), blk, 0, stream, values, vbf, n4_act);
    hipLaunchKernelGGL(cvt_kernel, dim3(1024), blk, 0, stream, w_v, wvbf, n4_w);
    hipLaunchKernelGGL((gemm_mixed<0>), dim3(64, 8), blk, 0, stream, wvbf, vbf, b_v, Vt);
    hipLaunchKernelGGL(attn7_kernel, dim3(16, 32), dim3(512), 0, stream,
                       Qhi, Qlo, Khi, Klo, Vt, Mb);
    hipLaunchKernelGGL((gemm_mixed<1>), dim3(16, 32), blk, 0, stream, Mb, w_o, b_o, (float*)d_out);
}

// Round 8
// 197.573 us; speedup vs baseline: 1.2096x; 1.1255x over previous
//
#include <hip/hip_runtime.h>

typedef __attribute__((ext_vector_type(8))) short bf16x8;
typedef __attribute__((ext_vector_type(4))) short short4v;
typedef __attribute__((ext_vector_type(4))) float f32x4;
typedef __attribute__((ext_vector_type(16))) float f32x16;
typedef __attribute__((ext_vector_type(4))) float float4v;
typedef unsigned short ushort_t;

__device__ __forceinline__ unsigned short f2bf(float x) {
    unsigned u = __float_as_uint(x);
    return (unsigned short)((u + 0x7fffu + ((u >> 16) & 1u)) >> 16);
}
__device__ __forceinline__ float bf2f(unsigned short b) {
    return __uint_as_float(((unsigned)b) << 16);
}
__device__ __forceinline__ f32x4 mfma16(bf16x8 a, bf16x8 b, f32x4 c) {
    return __builtin_amdgcn_mfma_f32_16x16x32_bf16(a, b, c, 0, 0, 0);
}
__device__ __forceinline__ f32x16 mfma32(bf16x8 a, bf16x8 b, f32x16 c) {
    return __builtin_amdgcn_mfma_f32_32x32x16_bf16(a, b, c, 0, 0, 0);
}
__device__ __forceinline__ unsigned cvtpk(float lo, float hi) {
    unsigned r;
    asm("v_cvt_pk_bf16_f32 %0, %1, %2" : "=v"(r) : "v"(lo), "v"(hi));
    return r;
}
__device__ __forceinline__ bf16x8 pack4(unsigned w0, unsigned w1, unsigned w2, unsigned w3) {
    union { unsigned u[4]; bf16x8 v; } c;
    c.u[0] = w0; c.u[1] = w1; c.u[2] = w2; c.u[3] = w3;
    return c.v;
}

constexpr int GK = 1024;

// ------------------------------------------------------------------
// Batched elementwise split: two tensors in one launch.
// blocks [0,halfgrid) -> tensor 0, rest -> tensor 1. n4 = N/4 (same).
// ------------------------------------------------------------------
__global__ __launch_bounds__(256)
void split2_kernel(const float* __restrict__ in0, ushort_t* __restrict__ hi0,
                   ushort_t* __restrict__ lo0,
                   const float* __restrict__ in1, ushort_t* __restrict__ hi1,
                   ushort_t* __restrict__ lo1, int n4, int halfgrid)
{
    const float* in; ushort_t* hi; ushort_t* lo;
    int bx = blockIdx.x;
    if (bx < halfgrid) { in = in0; hi = hi0; lo = lo0; }
    else               { in = in1; hi = hi1; lo = lo1; bx -= halfgrid; }
    int i = bx * 256 + threadIdx.x;
    const int stride = halfgrid * 256;
    for (; i < n4; i += stride) {
        float4v v = ((const float4v*)in)[i];
        short4v h, l;
        #pragma unroll
        for (int j = 0; j < 4; ++j) {
            unsigned short hb = f2bf(v[j]);
            h[j] = (short)hb;
            l[j] = (short)f2bf(v[j] - bf2f(hb));
        }
        ((short4v*)hi)[i] = h;
        ((short4v*)lo)[i] = l;
    }
}

// ------------------------------------------------------------------
// Batched convert: f32 -> bf16 for two tensors (different sizes).
// ------------------------------------------------------------------
__global__ __launch_bounds__(256)
void cvt2_kernel(const float* __restrict__ in0, ushort_t* __restrict__ out0, int n4_0,
                 const float* __restrict__ in1, ushort_t* __restrict__ out1, int n4_1,
                 int halfgrid)
{
    const float* in; ushort_t* out; int n4;
    int bx = blockIdx.x, hg;
    if (bx < halfgrid) { in = in0; out = out0; n4 = n4_0; hg = halfgrid; }
    else { in = in1; out = out1; n4 = n4_1; bx -= halfgrid; hg = gridDim.x - halfgrid; }
    int i = bx * 256 + threadIdx.x;
    const int stride = hg * 256;
    for (; i < n4; i += stride) {
        float4v v = ((const float4v*)in)[i];
        short4v h;
        #pragma unroll
        for (int j = 0; j < 4; ++j) h[j] = (short)f2bf(v[j]);
        ((short4v*)out)[i] = h;
    }
}

// ------------------------------------------------------------------
// Batched split GEMM (Q-proj z=0, K-proj z=1): pre-split bf16 inputs,
// 3-MFMA hi/lo, reg-prefetch pipeline. Q writes hi+lo; K writes hi only.
// M=4096, N=K=1024, BM=128, BN=64, BK=64.
// ------------------------------------------------------------------
constexpr int SBM = 128, SBN = 64, SLD = 72;

__global__ __launch_bounds__(256)
void gemm_splitQK(const ushort_t* __restrict__ qAhi, const ushort_t* __restrict__ qAlo,
                  const ushort_t* __restrict__ qBhi, const ushort_t* __restrict__ qBlo,
                  const float* __restrict__ qbias,
                  ushort_t* __restrict__ qOhi, ushort_t* __restrict__ qOlo,
                  const ushort_t* __restrict__ kAhi, const ushort_t* __restrict__ kAlo,
                  const ushort_t* __restrict__ kBhi, const ushort_t* __restrict__ kBlo,
                  const float* __restrict__ kbias, ushort_t* __restrict__ kOhi)
{
    const int z = blockIdx.z;
    const ushort_t* Ahi = z ? kAhi : qAhi;
    const ushort_t* Alo = z ? kAlo : qAlo;
    const ushort_t* Bhi = z ? kBhi : qBhi;
    const ushort_t* Blo = z ? kBlo : qBlo;
    const float*    bias = z ? kbias : qbias;
    ushort_t*       Ohi = z ? kOhi : qOhi;
    ushort_t*       Olo = z ? (ushort_t*)nullptr : qOlo;

    __shared__ alignas(16) short Ah[SBM * SLD], Al[SBM * SLD];
    __shared__ alignas(16) short Bh[SBN * SLD], Bl[SBN * SLD];

    const int tid = threadIdx.x, lane = tid & 63, wv = tid >> 6;
    const int lr = lane & 15, lg = lane >> 4;
    const int m0 = blockIdx.y * SBM, n0 = blockIdx.x * SBN;
    const int wm = (wv >> 1) * 64, wn = (wv & 1) * 32;
    const int r8 = tid >> 3, c8 = (tid & 7) * 8;

    f32x4 acc[4][2] = {};
    bf16x8 pah[4], pal[4], pbh[2], pbl[2];

    auto load_tiles = [&](int k0) {
        #pragma unroll
        for (int i = 0; i < 4; ++i) {
            const size_t off = (size_t)(m0 + r8 + 32 * i) * GK + k0 + c8;
            pah[i] = *(const bf16x8*)(Ahi + off);
            pal[i] = *(const bf16x8*)(Alo + off);
        }
        #pragma unroll
        for (int i = 0; i < 2; ++i) {
            const size_t off = (size_t)(n0 + r8 + 32 * i) * GK + k0 + c8;
            pbh[i] = *(const bf16x8*)(Bhi + off);
            pbl[i] = *(const bf16x8*)(Blo + off);
        }
    };

    load_tiles(0);

    for (int k0 = 0; k0 < GK; k0 += 64) {
        __syncthreads();
        #pragma unroll
        for (int i = 0; i < 4; ++i) {
            *(bf16x8*)(Ah + (r8 + 32 * i) * SLD + c8) = pah[i];
            *(bf16x8*)(Al + (r8 + 32 * i) * SLD + c8) = pal[i];
        }
        #pragma unroll
        for (int i = 0; i < 2; ++i) {
            *(bf16x8*)(Bh + (r8 + 32 * i) * SLD + c8) = pbh[i];
            *(bf16x8*)(Bl + (r8 + 32 * i) * SLD + c8) = pbl[i];
        }
        __syncthreads();
        if (k0 + 64 < GK) load_tiles(k0 + 64);

        #pragma unroll
        for (int ks = 0; ks < 2; ++ks) {
            bf16x8 af[4], afl[4], bfr[2], bfl[2];
            #pragma unroll
            for (int mi = 0; mi < 4; ++mi) {
                const int row = wm + mi * 16 + lr;
                af[mi]  = *(const bf16x8*)(Ah + row * SLD + ks * 32 + lg * 8);
                afl[mi] = *(const bf16x8*)(Al + row * SLD + ks * 32 + lg * 8);
            }
            #pragma unroll
            for (int ni = 0; ni < 2; ++ni) {
                const int row = wn + ni * 16 + lr;
                bfr[ni] = *(const bf16x8*)(Bh + row * SLD + ks * 32 + lg * 8);
                bfl[ni] = *(const bf16x8*)(Bl + row * SLD + ks * 32 + lg * 8);
            }
            #pragma unroll
            for (int mi = 0; mi < 4; ++mi)
                #pragma unroll
                for (int ni = 0; ni < 2; ++ni) {
                    acc[mi][ni] = mfma16(af[mi],  bfr[ni], acc[mi][ni]);
                    acc[mi][ni] = mfma16(af[mi],  bfl[ni], acc[mi][ni]);
                    acc[mi][ni] = mfma16(afl[mi], bfr[ni], acc[mi][ni]);
                }
        }
    }

    #pragma unroll
    for (int mi = 0; mi < 4; ++mi)
        #pragma unroll
        for (int ni = 0; ni < 2; ++ni) {
            const int gr = m0 + wm + mi * 16 + lg * 4;
            const int gc = n0 + wn + ni * 16 + lr;
            const float bv = bias[gc];
            #pragma unroll
            for (int r = 0; r < 4; ++r) {
                float val = acc[mi][ni][r] + bv;
                unsigned short hb = f2bf(val);
                Ohi[(size_t)(gr + r) * GK + gc] = hb;
                if (Olo) Olo[(size_t)(gr + r) * GK + gc] = f2bf(val - bf2f(hb));
            }
        }
}

// ------------------------------------------------------------------
// Mixed GEMM, plain bf16 single-MFMA, reg-prefetch pipeline.
// MODE 0 (V^T): A = w_v bf16, B = values bf16, out bf16 ld 4096, bias/ROW.
// MODE 1 (O):   A = Mb bf16, B = w_o f32, out f32 ld 1024, bias/COL.
// ------------------------------------------------------------------
template<int MODE>
__global__ __launch_bounds__(256)
void gemm_mixed(const ushort_t* __restrict__ Ap, const void* __restrict__ Bp,
                const float* __restrict__ bias, void* __restrict__ Op)
{
    __shared__ alignas(16) short Ah[SBM * SLD];
    __shared__ alignas(16) short Bh[SBN * SLD];

    const int tid = threadIdx.x, lane = tid & 63, wv = tid >> 6;
    const int lr = lane & 15, lg = lane >> 4;
    const int m0 = blockIdx.y * SBM, n0 = blockIdx.x * SBN;
    const int wm = (wv >> 1) * 64, wn = (wv & 1) * 32;
    const int r8 = tid >> 3, c8 = (tid & 7) * 8;
    const int r16 = tid >> 4, c4 = (tid & 15) * 4;

    f32x4 acc[4][2] = {};
    bf16x8 pa[4], pb[2];
    float4v pbf[4];

    auto load_tiles = [&](int k0) {
        #pragma unroll
        for (int i = 0; i < 4; ++i)
            pa[i] = *(const bf16x8*)(Ap + (size_t)(m0 + r8 + 32 * i) * GK + k0 + c8);
        if (MODE == 0) {
            const ushort_t* B = (const ushort_t*)Bp;
            #pragma unroll
            for (int i = 0; i < 2; ++i)
                pb[i] = *(const bf16x8*)(B + (size_t)(n0 + r8 + 32 * i) * GK + k0 + c8);
        } else {
            const float* B = (const float*)Bp;
            #pragma unroll
            for (int i = 0; i < 4; ++i)
                pbf[i] = *(const float4v*)(B + (size_t)(n0 + r16 + 16 * i) * GK + k0 + c4);
        }
    };

    load_tiles(0);

    for (int k0 = 0; k0 < GK; k0 += 64) {
        __syncthreads();
        #pragma unroll
        for (int i = 0; i < 4; ++i)
            *(bf16x8*)(Ah + (r8 + 32 * i) * SLD + c8) = pa[i];
        if (MODE == 0) {
            #pragma unroll
            for (int i = 0; i < 2; ++i)
                *(bf16x8*)(Bh + (r8 + 32 * i) * SLD + c8) = pb[i];
        } else {
            #pragma unroll
            for (int i = 0; i < 4; ++i) {
                short4v h;
                #pragma unroll
                for (int j = 0; j < 4; ++j) h[j] = (short)f2bf(pbf[i][j]);
                *(short4v*)(Bh + (r16 + 16 * i) * SLD + c4) = h;
            }
        }
        __syncthreads();
        if (k0 + 64 < GK) load_tiles(k0 + 64);

        #pragma unroll
        for (int ks = 0; ks < 2; ++ks) {
            bf16x8 af[4], bfr[2];
            #pragma unroll
            for (int mi = 0; mi < 4; ++mi)
                af[mi] = *(const bf16x8*)(Ah + (wm + mi * 16 + lr) * SLD + ks * 32 + lg * 8);
            #pragma unroll
            for (int ni = 0; ni < 2; ++ni)
                bfr[ni] = *(const bf16x8*)(Bh + (wn + ni * 16 + lr) * SLD + ks * 32 + lg * 8);
            #pragma unroll
            for (int mi = 0; mi < 4; ++mi)
                #pragma unroll
                for (int ni = 0; ni < 2; ++ni)
                    acc[mi][ni] = mfma16(af[mi], bfr[ni], acc[mi][ni]);
        }
    }

    #pragma unroll
    for (int mi = 0; mi < 4; ++mi)
        #pragma unroll
        for (int ni = 0; ni < 2; ++ni) {
            const int gr = m0 + wm + mi * 16 + lg * 4;
            const int gc = n0 + wn + ni * 16 + lr;
            #pragma unroll
            for (int r = 0; r < 4; ++r) {
                if (MODE == 0) {
                    float val = acc[mi][ni][r] + bias[gr + r];
                    ((ushort_t*)Op)[(size_t)(gr + r) * 4096 + gc] = f2bf(val);
                } else {
                    float val = acc[mi][ni][r] + bias[gc];
                    ((float*)Op)[(size_t)(gr + r) * 1024 + gc] = val;
                }
            }
        }
}

// ------------------------------------------------------------------
// Flash attention v8: as v7b but K is plain bf16 (no Klo): QK^T is
// 2-MFMA (kh x qh + kh x ql). Score error ~9e-4 std in the exponent —
// inside the absmax budget (threshold 4.3e-3, prior floor 1e-3).
// 512 thr / 8 waves = 4 q-groups x 2 K-halves; QT=128; LDS merge.
// ------------------------------------------------------------------
constexpr int SEQ = 2048, DM = 1024;

__device__ __forceinline__ bf16x8 lds_rd(const short* base, int row, int chunk) {
    return *(const bf16x8*)(base + row * 64 + ((chunk * 8) ^ ((row & 7) << 3)));
}

__global__ __launch_bounds__(512, 4)
void attn8_kernel(const ushort_t* __restrict__ Qhi, const ushort_t* __restrict__ Qlo,
                  const ushort_t* __restrict__ Khi,
                  const ushort_t* __restrict__ Vt,  ushort_t* __restrict__ Mrg)
{
    __shared__ alignas(16) float smem_f[8704];        // 34816 B (merge-sized)
    short* smem = (short*)smem_f;
    short* Ksh = smem;                                // staging: 2 x 8 KB
    short* Vsm = smem + 4096;

    const int tid = threadIdx.x, lane = tid & 63, wv = tid >> 6;
    const int l31 = lane & 31, lg2 = lane >> 5;
    const int qg = wv >> 1, khalf = wv & 1;

    const int f = blockIdx.y * 16 + blockIdx.x;      // 0..511
    const int g = (f & 7) * 64 + (f >> 3);           // bijective XCD swizzle
    const int qt = g & 15, bh = g >> 4;
    const int b = bh >> 4, h = bh & 15;
    const size_t seq0 = (size_t)b * SEQ;
    const int col0 = h * 64;

    // Q fragments (B-operand): q = l31, k = kc*16 + lg2*8 + j
    const int qrow = qt * 128 + qg * 32 + l31;
    bf16x8 qh[4], ql[4];
    #pragma unroll
    for (int kc = 0; kc < 4; ++kc) {
        const size_t off = (seq0 + qrow) * DM + col0 + kc * 16 + lg2 * 8;
        qh[kc] = *(const bf16x8*)(Qhi + off);
        ql[kc] = *(const bf16x8*)(Qlo + off);
    }

    f32x16 accT0 = {}, accT1 = {};      // O^T: col=q, rows d / d+32
    float m_run = -1e30f, l_run = 0.f;  // m on scaled scores; l lane-partial

    // staging: 512 thr cover one 64x64 K tile + one V tile (1 bf16x8 each)
    const int sr = tid >> 3, sc8 = (tid & 7) * 8;
    const int kb = khalf * 32;          // wave's key rows in LDS
    const int cb = khalf * 4;           // wave's V key-chunk base

    bf16x8 gkh, gvv;
    {
        gkh = *(const bf16x8*)(Khi + (seq0 + sr) * DM + col0 + sc8);
        gvv = *(const bf16x8*)(Vt + (size_t)(col0 + sr) * 4096 + seq0 + sc8);
    }

    for (int kt = 0; kt < SEQ; kt += 64) {
        __syncthreads();
        {
            const int wi = sr * 64 + (sc8 ^ ((sr & 7) << 3));
            *(bf16x8*)(Ksh + wi) = gkh;
            *(bf16x8*)(Vsm + wi) = gvv;
        }
        __syncthreads();

        {   // prefetch next tile
            const int ktn = (kt + 64 < SEQ) ? kt + 64 : kt;
            gkh = *(const bf16x8*)(Khi + (seq0 + ktn + sr) * DM + col0 + sc8);
            gvv = *(const bf16x8*)(Vt + (size_t)(col0 + sr) * 4096 + seq0 + ktn + sc8);
        }

        // ---- S^T for this wave's 32 keys: 2-MFMA (kh x qh + kh x ql) ----
        f32x16 s0 = {};
        #pragma unroll
        for (int kc = 0; kc < 4; ++kc) {
            const int c = kc * 2 + lg2;
            bf16x8 kh0 = lds_rd(Ksh, kb + l31, c);
            s0 = mfma32(kh0, qh[kc], s0);
            s0 = mfma32(kh0, ql[kc], s0);
        }

        // ---- online softmax, defer-max ----
        float mx = s0[0];
        #pragma unroll
        for (int i = 1; i < 16; ++i) mx = fmaxf(mx, s0[i]);
        float mxs = mx * 0.125f;
        mxs = fmaxf(mxs, __shfl_xor(mxs, 32));
        if (__any(mxs > m_run + 6.0f)) {
            const float mn    = fmaxf(m_run, mxs);
            const float alpha = __expf(m_run - mn);
            m_run = mn;
            l_run *= alpha;
            #pragma unroll
            for (int i = 0; i < 16; ++i) { accT0[i] *= alpha; accT1[i] *= alpha; }
        }
        float rs = 0.f;
        #pragma unroll
        for (int i = 0; i < 16; ++i) {
            float p = __expf(fmaf(s0[i], 0.125f, -m_run));
            s0[i] = p; rs += p;
        }
        l_run += rs;

        // ---- pack P (32 keys) -> pa[2] PV B-frags ----
        unsigned pk0[4][2];
        #pragma unroll
        for (int m = 0; m < 4; ++m) {
            pk0[m][0] = cvtpk(s0[4 * m],     s0[4 * m + 1]);
            pk0[m][1] = cvtpk(s0[4 * m + 2], s0[4 * m + 3]);
        }
        bf16x8 pa[2];
        #pragma unroll
        for (int u = 0; u < 2; ++u) {
            const unsigned pe0 = pk0[2 * u][0],     pe1 = pk0[2 * u][1];
            const unsigned po0 = pk0[2 * u + 1][0], po1 = pk0[2 * u + 1][1];
            const unsigned sd0 = lg2 ? pe0 : po0;
            const unsigned sd1 = lg2 ? pe1 : po1;
            const unsigned rc0 = (unsigned)__shfl_xor((int)sd0, 32);
            const unsigned rc1 = (unsigned)__shfl_xor((int)sd1, 32);
            const unsigned a0 = lg2 ? rc0 : pe0;
            const unsigned a1 = lg2 ? rc1 : pe1;
            const unsigned a2 = lg2 ? po0 : rc0;
            const unsigned a3 = lg2 ? po1 : rc1;
            pa[u] = pack4(a0, a1, a2, a3);
        }

        // ---- O^T += V^T P over this wave's keys ----
        #pragma unroll
        for (int u = 0; u < 2; ++u) {
            const int c = cb + u * 2 + lg2;
            bf16x8 v0 = lds_rd(Vsm, l31,      c);
            bf16x8 v1 = lds_rd(Vsm, l31 + 32, c);
            accT0 = mfma32(v0, pa[u], accT0);
            accT1 = mfma32(v1, pa[u], accT1);
        }
    }

    // ---- merge khalf pairs via LDS (34816 B), then store ----
    const float lfull = l_run + __shfl_xor(l_run, 32);
    float* slot = smem_f + (qg * 64 + lane) * 34;
    __syncthreads();
    if (khalf == 1) {
        slot[0] = m_run; slot[1] = lfull;
        #pragma unroll
        for (int i = 0; i < 16; ++i) { slot[2 + i] = accT0[i]; slot[18 + i] = accT1[i]; }
    }
    __syncthreads();
    if (khalf == 0) {
        const float mCp = slot[0], lp = slot[1];
        const float mn = fmaxf(m_run, mCp);
        const float a0 = __expf(m_run - mn);
        const float a1 = __expf(mCp - mn);
        const float inv = 1.0f / (lfull * a0 + lp * a1);
        #pragma unroll
        for (int reg = 0; reg < 16; ++reg) {
            const int d = (reg & 3) + 8 * (reg >> 2) + 4 * lg2;
            float o0 = (accT0[reg] * a0 + slot[2 + reg]  * a1) * inv;
            float o1 = (accT1[reg] * a0 + slot[18 + reg] * a1) * inv;
            Mrg[(seq0 + qrow) * DM + col0 + d]      = f2bf(o0);
            Mrg[(seq0 + qrow) * DM + col0 + d + 32] = f2bf(o1);
        }
    }
}

// ------------------------------------------------------------------
// Workspace map (48 MB) — lifetimes:
//  ws[0,8)   q_hi            -> (dead after gemmQK)  -> Vt
//  ws[8,16)  q_lo            -> dead after gemmQK
//  ws[16,24) Qhi   ws[24,32) Qlo        (live until attn)
//  ws[32,40) Khi                         (live until attn)
//  ws[40,42) wq_hi [42,44) wq_lo [44,46) wk_hi [46,48) wk_lo
//            -> (dead after gemmQK) -> Mb [40,48)
//  d_out[0,8)  k_hi -> vbf ; d_out[8,16) k_lo -> wvbf (dead before gemmO)
// ------------------------------------------------------------------
extern "C" void kernel_launch(void* const* d_in, const int* in_sizes, int n_in,
                              void* d_out, int out_size, void* d_ws, size_t ws_size,
                              hipStream_t stream)
{
    const float* queries = (const float*)d_in[0];
    const float* keys    = (const float*)d_in[1];
    const float* values  = (const float*)d_in[2];
    const float* w_q = (const float*)d_in[3];
    const float* b_q = (const float*)d_in[4];
    const float* w_k = (const float*)d_in[5];
    const float* b_k = (const float*)d_in[6];
    const float* w_v = (const float*)d_in[7];
    const float* b_v = (const float*)d_in[8];
    const float* w_o = (const float*)d_in[9];
    const float* b_o = (const float*)d_in[10];

    const size_t MB = 1u << 20;
    char* ws = (char*)d_ws;
    ushort_t* q_hi  = (ushort_t*)(ws);
    ushort_t* q_lo  = (ushort_t*)(ws + 8 * MB);
    ushort_t* Qhi   = (ushort_t*)(ws + 16 * MB);
    ushort_t* Qlo   = (ushort_t*)(ws + 24 * MB);
    ushort_t* Khi   = (ushort_t*)(ws + 32 * MB);
    ushort_t* wq_hi = (ushort_t*)(ws + 40 * MB);
    ushort_t* wq_lo = (ushort_t*)(ws + 42 * MB);
    ushort_t* wk_hi = (ushort_t*)(ws + 44 * MB);
    ushort_t* wk_lo = (ushort_t*)(ws + 46 * MB);
    ushort_t* Vt    = (ushort_t*)(ws);             // after gemmQK
    ushort_t* Mb    = (ushort_t*)(ws + 40 * MB);   // after gemmQK
    ushort_t* k_hi  = (ushort_t*)d_out;
    ushort_t* k_lo  = (ushort_t*)((char*)d_out + 8 * MB);
    ushort_t* vbf   = (ushort_t*)d_out;                    // after gemmQK
    ushort_t* wvbf  = (ushort_t*)((char*)d_out + 8 * MB);  // after gemmQK

    const int n4_act = 4096 * 1024 / 4, n4_w = 1024 * 1024 / 4;
    dim3 blk(256);

    // activations + weights split (batched)
    hipLaunchKernelGGL(split2_kernel, dim3(4096), blk, 0, stream,
                       queries, q_hi, q_lo, keys, k_hi, k_lo, n4_act, 2048);
    hipLaunchKernelGGL(split2_kernel, dim3(2048), blk, 0, stream,
                       w_q, wq_hi, wq_lo, w_k, wk_hi, wk_lo, n4_w, 1024);
    // Q-proj (hi+lo out) and K-proj (hi out) in one launch
    hipLaunchKernelGGL(gemm_splitQK, dim3(16, 32, 2), blk, 0, stream,
                       q_hi, q_lo, wq_hi, wq_lo, b_q, Qhi, Qlo,
                       k_hi, k_lo, wk_hi, wk_lo, b_k, Khi);
    // values + w_v to bf16 (d_out scratch now dead)
    hipLaunchKernelGGL(cvt2_kernel, dim3(2560), blk, 0, stream,
                       values, vbf, n4_act, w_v, wvbf, n4_w, 2048);
    hipLaunchKernelGGL((gemm_mixed<0>), dim3(64, 8), blk, 0, stream, wvbf, vbf, b_v, Vt);
    hipLaunchKernelGGL(attn8_kernel, dim3(16, 32), dim3(512), 0, stream,
                       Qhi, Qlo, Khi, Vt, Mb);
    hipLaunchKernelGGL((gemm_mixed<1>), dim3(16, 32), blk, 0, stream, Mb, w_o, b_o, (float*)d_out);
}

// Round 9
// 138.939 us; speedup vs baseline: 1.7200x; 1.4220x over previous
//
#include <hip/hip_runtime.h>

typedef __attribute__((ext_vector_type(8))) short bf16x8;
typedef __attribute__((ext_vector_type(4))) short short4v;
typedef __attribute__((ext_vector_type(4))) float f32x4;
typedef __attribute__((ext_vector_type(16))) float f32x16;
typedef __attribute__((ext_vector_type(4))) float float4v;
typedef unsigned short ushort_t;

__device__ __forceinline__ unsigned short f2bf(float x) {
    unsigned u = __float_as_uint(x);
    return (unsigned short)((u + 0x7fffu + ((u >> 16) & 1u)) >> 16);
}
__device__ __forceinline__ f32x4 mfma16(bf16x8 a, bf16x8 b, f32x4 c) {
    return __builtin_amdgcn_mfma_f32_16x16x32_bf16(a, b, c, 0, 0, 0);
}
__device__ __forceinline__ f32x16 mfma32(bf16x8 a, bf16x8 b, f32x16 c) {
    return __builtin_amdgcn_mfma_f32_32x32x16_bf16(a, b, c, 0, 0, 0);
}
__device__ __forceinline__ unsigned cvtpk(float lo, float hi) {
    unsigned r;
    asm("v_cvt_pk_bf16_f32 %0, %1, %2" : "=v"(r) : "v"(lo), "v"(hi));
    return r;
}
__device__ __forceinline__ bf16x8 pack4(unsigned w0, unsigned w1, unsigned w2, unsigned w3) {
    union { unsigned u[4]; bf16x8 v; } c;
    c.u[0] = w0; c.u[1] = w1; c.u[2] = w2; c.u[3] = w3;
    return c.v;
}

constexpr int GK = 1024;

// ------------------------------------------------------------------
// cvt7: all f32 inputs -> bf16 in one launch. Blocks partitioned so
// every block does 8 float4 iterations (activations 512 blk, weights 128).
// ------------------------------------------------------------------
__global__ __launch_bounds__(256)
void cvt7_kernel(const float* __restrict__ i0, ushort_t* __restrict__ o0,
                 const float* __restrict__ i1, ushort_t* __restrict__ o1,
                 const float* __restrict__ i2, ushort_t* __restrict__ o2,
                 const float* __restrict__ i3, ushort_t* __restrict__ o3,
                 const float* __restrict__ i4, ushort_t* __restrict__ o4,
                 const float* __restrict__ i5, ushort_t* __restrict__ o5,
                 const float* __restrict__ i6, ushort_t* __restrict__ o6)
{
    const float* in; ushort_t* out; int n4, nb, bx = blockIdx.x;
    if      (bx < 512)  { in = i0; out = o0; n4 = 1048576; nb = 512; }
    else if (bx < 1024) { in = i1; out = o1; n4 = 1048576; nb = 512; bx -= 512; }
    else if (bx < 1536) { in = i2; out = o2; n4 = 1048576; nb = 512; bx -= 1024; }
    else if (bx < 1664) { in = i3; out = o3; n4 = 262144;  nb = 128; bx -= 1536; }
    else if (bx < 1792) { in = i4; out = o4; n4 = 262144;  nb = 128; bx -= 1664; }
    else if (bx < 1920) { in = i5; out = o5; n4 = 262144;  nb = 128; bx -= 1792; }
    else                { in = i6; out = o6; n4 = 262144;  nb = 128; bx -= 1920; }
    int i = bx * 256 + threadIdx.x;
    const int stride = nb * 256;
    for (; i < n4; i += stride) {
        float4v v = ((const float4v*)in)[i];
        short4v h;
        #pragma unroll
        for (int j = 0; j < 4; ++j) h[j] = (short)f2bf(v[j]);
        ((short4v*)out)[i] = h;
    }
}

// ------------------------------------------------------------------
// Plain bf16 GEMM, 128x128 tile, BK=64, reg-prefetch pipeline,
// two parameter sets selected by blockIdx.z (for QK z-batching).
// C[m][n] = sum_k A[m][k] B[n][k] + bias.
// OUT_MODE 0: bf16 out ld 1024, bias per col   (Q-proj, K-proj)
// OUT_MODE 1: bf16 out ld 4096, bias per row   (V^T: A=w_v, B=values)
// OUT_MODE 2: f32  out ld 1024, bias per col   (O-proj)
// ------------------------------------------------------------------
constexpr int GLD = 72;

template<int OUT_MODE>
__global__ __launch_bounds__(256)
void gemm_bf16(const ushort_t* __restrict__ A0, const ushort_t* __restrict__ B0,
               const float* __restrict__ bias0, void* __restrict__ O0,
               const ushort_t* __restrict__ A1, const ushort_t* __restrict__ B1,
               const float* __restrict__ bias1, void* __restrict__ O1)
{
    const int z = blockIdx.z;
    const ushort_t* A = z ? A1 : A0;
    const ushort_t* B = z ? B1 : B0;
    const float* bias = z ? bias1 : bias0;
    void* O = z ? O1 : O0;

    __shared__ alignas(16) short Ah[128 * GLD];
    __shared__ alignas(16) short Bh[128 * GLD];

    const int tid = threadIdx.x, lane = tid & 63, wv = tid >> 6;
    const int lr = lane & 15, lg = lane >> 4;
    const int m0 = blockIdx.y * 128, n0 = blockIdx.x * 128;
    const int wm = (wv >> 1) * 64, wn = (wv & 1) * 64;
    const int r8 = tid >> 3, c8 = (tid & 7) * 8;

    f32x4 acc[4][4] = {};
    bf16x8 pa[4], pb[4];

    auto load_tiles = [&](int k0) {
        #pragma unroll
        for (int i = 0; i < 4; ++i) {
            pa[i] = *(const bf16x8*)(A + (size_t)(m0 + r8 + 32 * i) * GK + k0 + c8);
            pb[i] = *(const bf16x8*)(B + (size_t)(n0 + r8 + 32 * i) * GK + k0 + c8);
        }
    };

    load_tiles(0);

    for (int k0 = 0; k0 < GK; k0 += 64) {
        __syncthreads();
        #pragma unroll
        for (int i = 0; i < 4; ++i) {
            *(bf16x8*)(Ah + (r8 + 32 * i) * GLD + c8) = pa[i];
            *(bf16x8*)(Bh + (r8 + 32 * i) * GLD + c8) = pb[i];
        }
        __syncthreads();
        if (k0 + 64 < GK) load_tiles(k0 + 64);

        #pragma unroll
        for (int ks = 0; ks < 2; ++ks) {
            bf16x8 af[4], bfr[4];
            #pragma unroll
            for (int mi = 0; mi < 4; ++mi)
                af[mi] = *(const bf16x8*)(Ah + (wm + mi * 16 + lr) * GLD + ks * 32 + lg * 8);
            #pragma unroll
            for (int ni = 0; ni < 4; ++ni)
                bfr[ni] = *(const bf16x8*)(Bh + (wn + ni * 16 + lr) * GLD + ks * 32 + lg * 8);
            #pragma unroll
            for (int mi = 0; mi < 4; ++mi)
                #pragma unroll
                for (int ni = 0; ni < 4; ++ni)
                    acc[mi][ni] = mfma16(af[mi], bfr[ni], acc[mi][ni]);
        }
    }

    #pragma unroll
    for (int mi = 0; mi < 4; ++mi)
        #pragma unroll
        for (int ni = 0; ni < 4; ++ni) {
            const int gr = m0 + wm + mi * 16 + lg * 4;
            const int gc = n0 + wn + ni * 16 + lr;
            #pragma unroll
            for (int r = 0; r < 4; ++r) {
                if (OUT_MODE == 0) {
                    float val = acc[mi][ni][r] + bias[gc];
                    ((ushort_t*)O)[(size_t)(gr + r) * 1024 + gc] = f2bf(val);
                } else if (OUT_MODE == 1) {
                    float val = acc[mi][ni][r] + bias[gr + r];
                    ((ushort_t*)O)[(size_t)(gr + r) * 4096 + gc] = f2bf(val);
                } else {
                    float val = acc[mi][ni][r] + bias[gc];
                    ((float*)O)[(size_t)(gr + r) * 1024 + gc] = val;
                }
            }
        }
}

// ------------------------------------------------------------------
// Flash attention v9: all-bf16. 512 thr / 8 waves = 4 q-groups x
// 2 K-halves; QT=128; QK^T = 4 mfma32/tile; in-register softmax
// (defer-max), cvtpk+shfl P-frags, LDS merge of khalf pairs.
// ------------------------------------------------------------------
constexpr int SEQ = 2048, DM = 1024;

__device__ __forceinline__ bf16x8 lds_rd(const short* base, int row, int chunk) {
    return *(const bf16x8*)(base + row * 64 + ((chunk * 8) ^ ((row & 7) << 3)));
}

__global__ __launch_bounds__(512, 4)
void attn9_kernel(const ushort_t* __restrict__ Qb, const ushort_t* __restrict__ Kb,
                  const ushort_t* __restrict__ Vt,  ushort_t* __restrict__ Mrg)
{
    __shared__ alignas(16) float smem_f[8704];        // 34816 B (merge-sized)
    short* smem = (short*)smem_f;
    short* Ksh = smem;                                // staging: 2 x 8 KB
    short* Vsm = smem + 4096;

    const int tid = threadIdx.x, lane = tid & 63, wv = tid >> 6;
    const int l31 = lane & 31, lg2 = lane >> 5;
    const int qg = wv >> 1, khalf = wv & 1;

    const int f = blockIdx.y * 16 + blockIdx.x;      // 0..511
    const int g = (f & 7) * 64 + (f >> 3);           // bijective XCD swizzle
    const int qt = g & 15, bh = g >> 4;
    const int b = bh >> 4, h = bh & 15;
    const size_t seq0 = (size_t)b * SEQ;
    const int col0 = h * 64;

    // Q fragments (B-operand): q = l31, k = kc*16 + lg2*8 + j
    const int qrow = qt * 128 + qg * 32 + l31;
    bf16x8 qh[4];
    #pragma unroll
    for (int kc = 0; kc < 4; ++kc)
        qh[kc] = *(const bf16x8*)(Qb + (seq0 + qrow) * DM + col0 + kc * 16 + lg2 * 8);

    f32x16 accT0 = {}, accT1 = {};      // O^T: col=q, rows d / d+32
    float m_run = -1e30f, l_run = 0.f;  // m on scaled scores; l lane-partial

    const int sr = tid >> 3, sc8 = (tid & 7) * 8;
    const int kb = khalf * 32;          // wave's key rows in LDS
    const int cb = khalf * 4;           // wave's V key-chunk base

    bf16x8 gkh, gvv;
    {
        gkh = *(const bf16x8*)(Kb + (seq0 + sr) * DM + col0 + sc8);
        gvv = *(const bf16x8*)(Vt + (size_t)(col0 + sr) * 4096 + seq0 + sc8);
    }

    for (int kt = 0; kt < SEQ; kt += 64) {
        __syncthreads();
        {
            const int wi = sr * 64 + (sc8 ^ ((sr & 7) << 3));
            *(bf16x8*)(Ksh + wi) = gkh;
            *(bf16x8*)(Vsm + wi) = gvv;
        }
        __syncthreads();

        {   // prefetch next tile
            const int ktn = (kt + 64 < SEQ) ? kt + 64 : kt;
            gkh = *(const bf16x8*)(Kb + (seq0 + ktn + sr) * DM + col0 + sc8);
            gvv = *(const bf16x8*)(Vt + (size_t)(col0 + sr) * 4096 + seq0 + ktn + sc8);
        }

        // ---- S^T for this wave's 32 keys: 4 mfma32 ----
        f32x16 s0 = {};
        #pragma unroll
        for (int kc = 0; kc < 4; ++kc) {
            const int c = kc * 2 + lg2;
            bf16x8 kh0 = lds_rd(Ksh, kb + l31, c);
            s0 = mfma32(kh0, qh[kc], s0);
        }

        // ---- online softmax, defer-max ----
        float mx = s0[0];
        #pragma unroll
        for (int i = 1; i < 16; ++i) mx = fmaxf(mx, s0[i]);
        float mxs = mx * 0.125f;
        mxs = fmaxf(mxs, __shfl_xor(mxs, 32));
        if (__any(mxs > m_run + 6.0f)) {
            const float mn    = fmaxf(m_run, mxs);
            const float alpha = __expf(m_run - mn);
            m_run = mn;
            l_run *= alpha;
            #pragma unroll
            for (int i = 0; i < 16; ++i) { accT0[i] *= alpha; accT1[i] *= alpha; }
        }
        float rs = 0.f;
        #pragma unroll
        for (int i = 0; i < 16; ++i) {
            float p = __expf(fmaf(s0[i], 0.125f, -m_run));
            s0[i] = p; rs += p;
        }
        l_run += rs;

        // ---- pack P (32 keys) -> pa[2] PV B-frags ----
        unsigned pk0[4][2];
        #pragma unroll
        for (int m = 0; m < 4; ++m) {
            pk0[m][0] = cvtpk(s0[4 * m],     s0[4 * m + 1]);
            pk0[m][1] = cvtpk(s0[4 * m + 2], s0[4 * m + 3]);
        }
        bf16x8 pa[2];
        #pragma unroll
        for (int u = 0; u < 2; ++u) {
            const unsigned pe0 = pk0[2 * u][0],     pe1 = pk0[2 * u][1];
            const unsigned po0 = pk0[2 * u + 1][0], po1 = pk0[2 * u + 1][1];
            const unsigned sd0 = lg2 ? pe0 : po0;
            const unsigned sd1 = lg2 ? pe1 : po1;
            const unsigned rc0 = (unsigned)__shfl_xor((int)sd0, 32);
            const unsigned rc1 = (unsigned)__shfl_xor((int)sd1, 32);
            const unsigned a0 = lg2 ? rc0 : pe0;
            const unsigned a1 = lg2 ? rc1 : pe1;
            const unsigned a2 = lg2 ? po0 : rc0;
            const unsigned a3 = lg2 ? po1 : rc1;
            pa[u] = pack4(a0, a1, a2, a3);
        }

        // ---- O^T += V^T P over this wave's keys ----
        #pragma unroll
        for (int u = 0; u < 2; ++u) {
            const int c = cb + u * 2 + lg2;
            bf16x8 v0 = lds_rd(Vsm, l31,      c);
            bf16x8 v1 = lds_rd(Vsm, l31 + 32, c);
            accT0 = mfma32(v0, pa[u], accT0);
            accT1 = mfma32(v1, pa[u], accT1);
        }
    }

    // ---- merge khalf pairs via LDS (34816 B), then store ----
    const float lfull = l_run + __shfl_xor(l_run, 32);
    float* slot = smem_f + (qg * 64 + lane) * 34;
    __syncthreads();
    if (khalf == 1) {
        slot[0] = m_run; slot[1] = lfull;
        #pragma unroll
        for (int i = 0; i < 16; ++i) { slot[2 + i] = accT0[i]; slot[18 + i] = accT1[i]; }
    }
    __syncthreads();
    if (khalf == 0) {
        const float mCp = slot[0], lp = slot[1];
        const float mn = fmaxf(m_run, mCp);
        const float a0 = __expf(m_run - mn);
        const float a1 = __expf(mCp - mn);
        const float inv = 1.0f / (lfull * a0 + lp * a1);
        #pragma unroll
        for (int reg = 0; reg < 16; ++reg) {
            const int d = (reg & 3) + 8 * (reg >> 2) + 4 * lg2;
            float o0 = (accT0[reg] * a0 + slot[2 + reg]  * a1) * inv;
            float o1 = (accT1[reg] * a0 + slot[18 + reg] * a1) * inv;
            Mrg[(seq0 + qrow) * DM + col0 + d]      = f2bf(o0);
            Mrg[(seq0 + qrow) * DM + col0 + d + 32] = f2bf(o1);
        }
    }
}

// ------------------------------------------------------------------
// Workspace map (48 MB) — lifetimes:
//  ws[0,8)   q_bf  (cvt -> gemmQK)        -> Mb (attn -> gemmO)
//  ws[8,16)  k_bf  (cvt -> gemmQK)
//  ws[16,24) Qb    (gemmQK -> attn)
//  ws[24,32) Kb    (gemmQK -> attn)
//  ws[32,40) v_bf  (cvt -> gemmV)
//  ws[40,42) wq [42,44) wk  (cvt -> gemmQK)
//  ws[44,46) wv (cvt -> gemmV)  [46,48) wo (cvt -> gemmO)
//  d_out[0,8) Vt (gemmV -> attn; dead before gemmO writes f32 out)
// ------------------------------------------------------------------
extern "C" void kernel_launch(void* const* d_in, const int* in_sizes, int n_in,
                              void* d_out, int out_size, void* d_ws, size_t ws_size,
                              hipStream_t stream)
{
    const float* queries = (const float*)d_in[0];
    const float* keys    = (const float*)d_in[1];
    const float* values  = (const float*)d_in[2];
    const float* w_q = (const float*)d_in[3];
    const float* b_q = (const float*)d_in[4];
    const float* w_k = (const float*)d_in[5];
    const float* b_k = (const float*)d_in[6];
    const float* w_v = (const float*)d_in[7];
    const float* b_v = (const float*)d_in[8];
    const float* w_o = (const float*)d_in[9];
    const float* b_o = (const float*)d_in[10];

    const size_t MB = 1u << 20;
    char* ws = (char*)d_ws;
    ushort_t* q_bf = (ushort_t*)(ws);
    ushort_t* k_bf = (ushort_t*)(ws + 8 * MB);
    ushort_t* Qb   = (ushort_t*)(ws + 16 * MB);
    ushort_t* Kb   = (ushort_t*)(ws + 24 * MB);
    ushort_t* v_bf = (ushort_t*)(ws + 32 * MB);
    ushort_t* wq   = (ushort_t*)(ws + 40 * MB);
    ushort_t* wk   = (ushort_t*)(ws + 42 * MB);
    ushort_t* wvb  = (ushort_t*)(ws + 44 * MB);
    ushort_t* wo   = (ushort_t*)(ws + 46 * MB);
    ushort_t* Mb   = (ushort_t*)(ws);              // after gemmQK (q_bf dead)
    ushort_t* Vt   = (ushort_t*)d_out;             // dead before gemmO writes

    dim3 blk(256);

    // everything to bf16 in one pass
    hipLaunchKernelGGL(cvt7_kernel, dim3(2048), blk, 0, stream,
                       queries, q_bf, keys, k_bf, values, v_bf,
                       w_q, wq, w_k, wk, w_v, wvb, w_o, wo);
    // Q-proj + K-proj, z-batched, 128x128 tiles
    hipLaunchKernelGGL((gemm_bf16<0>), dim3(8, 32, 2), blk, 0, stream,
                       q_bf, wq, b_q, Qb, k_bf, wk, b_k, Kb);
    // V^T: A = w_v (M=1024), B = values (N=4096), out [d][seq]
    hipLaunchKernelGGL((gemm_bf16<1>), dim3(32, 8, 1), blk, 0, stream,
                       wvb, v_bf, b_v, Vt, wvb, v_bf, b_v, Vt);
    // attention
    hipLaunchKernelGGL(attn9_kernel, dim3(16, 32), dim3(512), 0, stream,
                       Qb, Kb, Vt, Mb);
    // O-proj -> d_out (f32)
    hipLaunchKernelGGL((gemm_bf16<2>), dim3(8, 32, 1), blk, 0, stream,
                       Mb, wo, b_o, (float*)d_out, Mb, wo, b_o, (float*)d_out);
}